// Round 2
// baseline (110.824 us; speedup 1.0000x reference)
//
#include <hip/hip_runtime.h>

constexpr int BLOCK = 256;
constexpr int IPT = 4;   // anchors per thread (4 independent dep-chains)
constexpr int BPB = 2;   // batches per block (work balancing across CUs)

__global__ __launch_bounds__(BLOCK, 4) void assign_cls_label_kernel(
    const float* __restrict__ anchorss,   // (B,N,4) y,x,h,w (or y1,x1,y2,x2 if !use_anchor)
    const float* __restrict__ gt_bboxess, // (B,A,4) y1,x1,y2,x2
    const int* __restrict__ gt_counts,    // (B,1)
    const int* __restrict__ use_anchor_p, // scalar
    int* __restrict__ out,                // (B,N)
    int N, int A, int B)
{
#pragma clang fp contract(off)
    extern __shared__ float4 s_box[];     // [BPB][A]
    __shared__ int s_count[BPB];

    const int tid = threadIdx.x;
    const int b0  = blockIdx.y * BPB;
    const int nb  = (B - b0 < BPB) ? (B - b0) : BPB;   // block-uniform

    // ---- stage gt boxes for this block's batches into LDS ----
    for (int i = tid; i < nb * A; i += BLOCK) {
        const int bb = i / A, gi = i - bb * A;
        s_box[i] = reinterpret_cast<const float4*>(gt_bboxess)[(size_t)(b0 + bb) * A + gi];
    }
    if (tid < nb) s_count[tid] = gt_counts[b0 + tid];

    const int use_anchor = use_anchor_p[0];
    const int base_n = blockIdx.x * (BLOCK * IPT) + tid;  // stride-BLOCK anchors -> coalesced

    // ---- issue ALL anchor loads up-front (HBM latency hides under staging + compute) ----
    float4 a[BPB][IPT];
#pragma unroll
    for (int bb = 0; bb < BPB; ++bb)
#pragma unroll
        for (int k = 0; k < IPT; ++k) {
            int n = base_n + k * BLOCK;
            if (n >= N) n = N - 1;                       // tail clamp (results discarded)
            if (bb < nb)
                a[bb][k] = reinterpret_cast<const float4*>(anchorss)[(size_t)(b0 + bb) * N + n];
        }

    __syncthreads();

    const float c26 = 1.0f / 67108864.0f;  // 2^-26: fl(inter/u)>=0.5 <=> inter-(0.5-2^-26)*u >= 0

    for (int bb = 0; bb < nb; ++bb) {
        float y1[IPT], x1[IPT], y2[IPT], x2[IPT], area[IPT], acc[IPT];
#pragma unroll
        for (int k = 0; k < IPT; ++k) {
            const float4 v = a[bb][k];
            if (use_anchor) {
                const float h = v.z, w = v.w;
                y1[k]   = v.x - h * 0.5f;   // same rounding as ref: y - h/2
                y2[k]   = y1[k] + h;
                x1[k]   = v.y - w * 0.5f;
                x2[k]   = x1[k] + w;
                area[k] = h * w;
            } else {
                y1[k] = v.x; x1[k] = v.y; y2[k] = v.z; x2[k] = v.w;
                area[k] = (y2[k] - y1[k]) * (x2[k] - x1[k]);
            }
            acc[k] = -1.0f;
        }

        const int count = s_count[bb];
        const float4* sb = s_box + bb * A;

        // register double-buffer: prefetch next gt box while computing current
        float4 g = sb[0];
        for (int gi = 0; gi < count; ++gi) {
            int ni = gi + 1; if (ni >= A) ni = A - 1;    // scalar clamp, stays in staged range
            const float4 gn = sb[ni];
            const float ga = (g.z - g.x) * (g.w - g.y);  // recompute area: 3 VALU, saves LDS read
#pragma unroll
            for (int k = 0; k < IPT; ++k) {
                const float yy1 = __builtin_amdgcn_fmed3f(y1[k], g.x, g.z);
                const float yy2 = __builtin_amdgcn_fmed3f(y2[k], g.x, g.z);
                const float xx1 = __builtin_amdgcn_fmed3f(x1[k], g.y, g.w);
                const float xx2 = __builtin_amdgcn_fmed3f(x2[k], g.y, g.w);
                const float dy    = yy2 - yy1;
                const float dx    = xx2 - xx1;
                const float inter = dy * dx;
                const float s     = area[k] + ga;        // ref assoc: (area+ga)-inter
                const float u     = s - inter;
                // sign-exact test for fl(inter/u) >= 0.5  (u > 0 guaranteed: area > 1e-4)
                const float e = fmaf(-0.5f, u, inter);   // Sterbenz-exact in the decision band
                const float r = fmaf(c26, u, e);         // sign == sign(inter - (0.5-2^-26)*u)
                acc[k] = fmaxf(acc[k], r);
            }
            g = gn;
        }

#pragma unroll
        for (int k = 0; k < IPT; ++k) {
            const int n = base_n + k * BLOCK;
            if (n < N) out[(size_t)(b0 + bb) * N + n] = (acc[k] >= 0.0f) ? 1 : 0;
        }
    }
}

extern "C" void kernel_launch(void* const* d_in, const int* in_sizes, int n_in,
                              void* d_out, int out_size, void* d_ws, size_t ws_size,
                              hipStream_t stream) {
    const float* anchorss   = (const float*)d_in[0];
    const float* gt_bboxess = (const float*)d_in[1];
    const int*   gt_counts  = (const int*)d_in[2];
    const int*   use_anchor = (const int*)d_in[3];
    int*         out        = (int*)d_out;

    const int B = in_sizes[2];              // gt_counts is (B,1)
    const int A = in_sizes[1] / (4 * B);    // gt_bboxess is (B,A,4)
    const int N = in_sizes[0] / (4 * B);    // anchorss   is (B,N,4)

    dim3 grid((N + BLOCK * IPT - 1) / (BLOCK * IPT), (B + BPB - 1) / BPB);
    size_t smem = (size_t)(BPB * A) * sizeof(float4);
    hipLaunchKernelGGL(assign_cls_label_kernel, grid, dim3(BLOCK), smem, stream,
                       anchorss, gt_bboxess, gt_counts, use_anchor, out, N, A, B);
}

// Round 3
// 98.912 us; speedup vs baseline: 1.1204x; 1.1204x over previous
//
#include <hip/hip_runtime.h>

constexpr int BLOCK = 256;
constexpr int IPT = 4;   // anchors per thread (4 independent dep-chains)
constexpr int BPB = 2;   // batches per block (work balancing across CUs)

__global__ __launch_bounds__(BLOCK, 4) void assign_cls_label_kernel(
    const float* __restrict__ anchorss,   // (B,N,4) y,x,h,w (or y1,x1,y2,x2 if !use_anchor)
    const float* __restrict__ gt_bboxess, // (B,A,4) y1,x1,y2,x2
    const int* __restrict__ gt_counts,    // (B,1)
    const int* __restrict__ use_anchor_p, // scalar
    int* __restrict__ out,                // (B,N)
    int N, int A, int B)
{
#pragma clang fp contract(off)
    extern __shared__ float4 s_box[];     // [BPB][A]
    __shared__ int s_count[BPB];

    const int tid = threadIdx.x;
    const int b0  = blockIdx.y * BPB;

    // ---- stage gt boxes for this block's batches into LDS ----
    const int nb = (B - b0 < BPB) ? (B - b0) : BPB;     // block-uniform
    for (int i = tid; i < nb * A; i += BLOCK) {
        const int bb = i / A, gi = i - bb * A;
        s_box[i] = reinterpret_cast<const float4*>(gt_bboxess)[(size_t)(b0 + bb) * A + gi];
    }
    if (tid < BPB) s_count[tid] = (tid < nb) ? gt_counts[b0 + tid] : 0;

    const int use_anchor = use_anchor_p[0];
    const int base_n = blockIdx.x * (BLOCK * IPT) + tid;  // stride-BLOCK anchors -> coalesced

    // ---- issue ALL anchor loads up-front; COMPILE-TIME indices only (rule #20:
    // runtime-indexed arrays spill to scratch -> 32MB of scratch traffic in round 2) ----
    float4 a[BPB][IPT];
#pragma unroll
    for (int bb = 0; bb < BPB; ++bb) {
#pragma unroll
        for (int k = 0; k < IPT; ++k) {
            int n = base_n + k * BLOCK;
            if (n >= N) n = N - 1;                       // tail clamp (results discarded)
            if (b0 + bb < B)
                a[bb][k] = reinterpret_cast<const float4*>(anchorss)[(size_t)(b0 + bb) * N + n];
        }
    }

    __syncthreads();

    const float c26 = 1.0f / 67108864.0f;  // 2^-26: fl(inter/u)>=0.5 <=> inter-(0.5-2^-26)*u >= 0

#pragma unroll
    for (int bb = 0; bb < BPB; ++bb) {
        if (b0 + bb < B) {
            float y1[IPT], x1[IPT], y2[IPT], x2[IPT], area[IPT], acc[IPT];
#pragma unroll
            for (int k = 0; k < IPT; ++k) {
                const float4 v = a[bb][k];
                if (use_anchor) {
                    const float h = v.z, w = v.w;
                    y1[k]   = v.x - h * 0.5f;   // same rounding as ref: y - h/2
                    y2[k]   = y1[k] + h;
                    x1[k]   = v.y - w * 0.5f;
                    x2[k]   = x1[k] + w;
                    area[k] = h * w;
                } else {
                    y1[k] = v.x; x1[k] = v.y; y2[k] = v.z; x2[k] = v.w;
                    area[k] = (y2[k] - y1[k]) * (x2[k] - x1[k]);
                }
                acc[k] = -1.0f;
            }

            const int count = s_count[bb];
            const float4* sb = s_box + bb * A;

            // register double-buffer: prefetch next gt box while computing current
            float4 g = sb[0];
            for (int gi = 0; gi < count; ++gi) {
                int ni = gi + 1; if (ni >= A) ni = A - 1;   // stays within staged range
                const float4 gn = sb[ni];
                const float ga = (g.z - g.x) * (g.w - g.y); // 3 VALU, saves an LDS read
#pragma unroll
                for (int k = 0; k < IPT; ++k) {
                    const float yy1 = __builtin_amdgcn_fmed3f(y1[k], g.x, g.z);
                    const float yy2 = __builtin_amdgcn_fmed3f(y2[k], g.x, g.z);
                    const float xx1 = __builtin_amdgcn_fmed3f(x1[k], g.y, g.w);
                    const float xx2 = __builtin_amdgcn_fmed3f(x2[k], g.y, g.w);
                    const float dy    = yy2 - yy1;
                    const float dx    = xx2 - xx1;
                    const float inter = dy * dx;
                    const float s     = area[k] + ga;       // ref assoc: (area+ga)-inter
                    const float u     = s - inter;
                    // sign-exact: fl(inter/u)>=0.5 <=> inter >= (0.5-2^-26)*u  (u>0 always)
                    const float e = fmaf(-0.5f, u, inter);  // Sterbenz-exact in decision band
                    const float r = fmaf(c26, u, e);        // sign == sign(inter-(0.5-2^-26)u)
                    acc[k] = fmaxf(acc[k], r);
                }
                g = gn;
            }

#pragma unroll
            for (int k = 0; k < IPT; ++k) {
                const int n = base_n + k * BLOCK;
                if (n < N) out[(size_t)(b0 + bb) * N + n] = (acc[k] >= 0.0f) ? 1 : 0;
            }
        }
    }
}

extern "C" void kernel_launch(void* const* d_in, const int* in_sizes, int n_in,
                              void* d_out, int out_size, void* d_ws, size_t ws_size,
                              hipStream_t stream) {
    const float* anchorss   = (const float*)d_in[0];
    const float* gt_bboxess = (const float*)d_in[1];
    const int*   gt_counts  = (const int*)d_in[2];
    const int*   use_anchor = (const int*)d_in[3];
    int*         out        = (int*)d_out;

    const int B = in_sizes[2];              // gt_counts is (B,1)
    const int A = in_sizes[1] / (4 * B);    // gt_bboxess is (B,A,4)
    const int N = in_sizes[0] / (4 * B);    // anchorss   is (B,N,4)

    dim3 grid((N + BLOCK * IPT - 1) / (BLOCK * IPT), (B + BPB - 1) / BPB);
    size_t smem = (size_t)(BPB * A) * sizeof(float4);
    hipLaunchKernelGGL(assign_cls_label_kernel, grid, dim3(BLOCK), smem, stream,
                       anchorss, gt_bboxess, gt_counts, use_anchor, out, N, A, B);
}

// Round 4
// 98.846 us; speedup vs baseline: 1.1212x; 1.0007x over previous
//
#include <hip/hip_runtime.h>

typedef float f32x2 __attribute__((ext_vector_type(2)));

constexpr int BLOCK = 256;
constexpr int IPT   = 2;   // anchors per thread, packed as one f32x2 lane-pair
constexpr int BPB   = 8;   // ALL batches per block -> every block has identical work

__global__ __launch_bounds__(BLOCK, 2) void assign_cls_label_kernel(
    const float* __restrict__ anchorss,   // (B,N,4) y,x,h,w (or y1,x1,y2,x2 if !use_anchor)
    const float* __restrict__ gt_bboxess, // (B,A,4) y1,x1,y2,x2
    const int* __restrict__ gt_counts,    // (B,1)
    const int* __restrict__ use_anchor_p, // scalar
    int* __restrict__ out,                // (B,N)
    int N, int A, int B)
{
#pragma clang fp contract(off)
    extern __shared__ float smem[];
    float4* s_box = (float4*)smem;         // [BPB][A]
    float*  s_ga  = smem + 4 * BPB * A;    // [BPB][A]
    __shared__ int s_count[BPB];

    const int tid = threadIdx.x;
    const int b0  = blockIdx.y * BPB;
    const int nbA = ((B - b0 < BPB) ? (B - b0) : BPB) * A;

    const int n0r = blockIdx.x * (BLOCK * IPT) + tid;   // coalesced: lane-contiguous
    const int n1r = n0r + BLOCK;
    const int n0  = (n0r < N) ? n0r : N - 1;            // tail clamp (stores guarded)
    const int n1  = (n1r < N) ? n1r : N - 1;

    // prefetch batch-0 anchors (independent of LDS staging, hides HBM latency)
    float4 an0 = ((const float4*)anchorss)[(size_t)b0 * N + n0];
    float4 an1 = ((const float4*)anchorss)[(size_t)b0 * N + n1];

    // stage gt boxes + areas for ALL batches (exact ref op order: two subs, one mul)
    for (int i = tid; i < nbA; i += BLOCK) {
        const int bb = i / A, gi = i - bb * A;
        float4 g = ((const float4*)gt_bboxess)[(size_t)(b0 + bb) * A + gi];
        s_box[i] = g;
        s_ga[i]  = (g.z - g.x) * (g.w - g.y);
    }
    if (tid < BPB) s_count[tid] = (b0 + tid < B) ? gt_counts[b0 + tid] : 0;

    const int use_anchor = use_anchor_p[0];
    __syncthreads();

    const float c26 = 1.0f / 67108864.0f;  // fl(i/u)>=0.5 <=> i-(0.5-2^-26)u >= 0 (sign-exact)
    const int   Am1 = A - 1;

    for (int bb = 0; bb < BPB; ++bb) {
        if (b0 + bb >= B) break;                       // uniform
        const float4 ac0 = an0, ac1 = an1;
        if (bb + 1 < BPB && b0 + bb + 1 < B) {         // rolling prefetch of next batch
            const float4* arow = (const float4*)anchorss + (size_t)(b0 + bb + 1) * N;
            an0 = arow[n0];
            an1 = arow[n1];
        }

        f32x2 Y1, X1, Y2, X2, AREA;
        if (use_anchor) {
            Y1.x = ac0.x - ac0.z * 0.5f;  Y1.y = ac1.x - ac1.z * 0.5f;  // y - h/2 (ref rounding)
            Y2.x = Y1.x + ac0.z;          Y2.y = Y1.y + ac1.z;
            X1.x = ac0.y - ac0.w * 0.5f;  X1.y = ac1.y - ac1.w * 0.5f;
            X2.x = X1.x + ac0.w;          X2.y = X1.y + ac1.w;
            AREA.x = ac0.z * ac0.w;       AREA.y = ac1.z * ac1.w;
        } else {
            Y1.x = ac0.x; Y1.y = ac1.x;   X1.x = ac0.y; X1.y = ac1.y;
            Y2.x = ac0.z; Y2.y = ac1.z;   X2.x = ac0.w; X2.y = ac1.w;
            AREA.x = (Y2.x - Y1.x) * (X2.x - X1.x);
            AREA.y = (Y2.y - Y1.y) * (X2.y - X1.y);
        }
        f32x2 ACC; ACC.x = -1.0f; ACC.y = -1.0f;

        const float4* sb    = s_box + bb * A;
        const float*  sga   = s_ga  + bb * A;
        const int     count = s_count[bb];

        // one gt vs the packed anchor pair: 8 scalar med3 + 6 packable vector ops + 2 max
        auto comp = [&](const float4 g, const float ga) {
            f32x2 yy1, yy2, xx1, xx2;
            yy1.x = __builtin_amdgcn_fmed3f(Y1.x, g.x, g.z);
            yy1.y = __builtin_amdgcn_fmed3f(Y1.y, g.x, g.z);
            yy2.x = __builtin_amdgcn_fmed3f(Y2.x, g.x, g.z);
            yy2.y = __builtin_amdgcn_fmed3f(Y2.y, g.x, g.z);
            xx1.x = __builtin_amdgcn_fmed3f(X1.x, g.y, g.w);
            xx1.y = __builtin_amdgcn_fmed3f(X1.y, g.y, g.w);
            xx2.x = __builtin_amdgcn_fmed3f(X2.x, g.y, g.w);
            xx2.y = __builtin_amdgcn_fmed3f(X2.y, g.y, g.w);
            f32x2 dy    = yy2 - yy1;
            f32x2 dx    = xx2 - xx1;
            f32x2 inter = dy * dx;
            f32x2 u     = (AREA + ga) - inter;         // ref assoc: (area+ga)-inter
            f32x2 hn; hn.x = -0.5f; hn.y = -0.5f;
            f32x2 cc; cc.x = c26;   cc.y = c26;
            f32x2 e = __builtin_elementwise_fma(u, hn, inter);  // Sterbenz-exact band
            f32x2 r = __builtin_elementwise_fma(u, cc, e);      // sign == sign(i-(0.5-2^-26)u)
            ACC = __builtin_elementwise_max(ACC, r);
        };

        // 4-deep banked register prefetch from LDS (named scalars: no runtime indexing)
        float4 gA0, gA1, gA2, gA3, gB0, gB1, gB2, gB3;
        float  aA0, aA1, aA2, aA3, aB0, aB1, aB2, aB3;

#define LOAD_BANK(G0,G1,G2,G3,Q0,Q1,Q2,Q3, base_) do {                       \
            int i0_ = (base_),   i1_ = (base_)+1, i2_ = (base_)+2, i3_ = (base_)+3; \
            i0_ = (i0_ < Am1) ? i0_ : Am1;  i1_ = (i1_ < Am1) ? i1_ : Am1;   \
            i2_ = (i2_ < Am1) ? i2_ : Am1;  i3_ = (i3_ < Am1) ? i3_ : Am1;   \
            G0 = sb[i0_]; Q0 = sga[i0_];  G1 = sb[i1_]; Q1 = sga[i1_];       \
            G2 = sb[i2_]; Q2 = sga[i2_];  G3 = sb[i3_]; Q3 = sga[i3_];       \
        } while (0)

        LOAD_BANK(gA0,gA1,gA2,gA3, aA0,aA1,aA2,aA3, 0);
        int gi = 0;
        while (gi + 8 <= count) {
            LOAD_BANK(gB0,gB1,gB2,gB3, aB0,aB1,aB2,aB3, gi + 4);
            comp(gA0,aA0); comp(gA1,aA1); comp(gA2,aA2); comp(gA3,aA3);
            LOAD_BANK(gA0,gA1,gA2,gA3, aA0,aA1,aA2,aA3, gi + 8);
            comp(gB0,aB0); comp(gB1,aB1); comp(gB2,aB2); comp(gB3,aB3);
            gi += 8;
        }
        const int rem = count - gi;                    // 0..7; bank A holds gi..gi+3
        if (rem > 4) LOAD_BANK(gB0,gB1,gB2,gB3, aB0,aB1,aB2,aB3, gi + 4);
        if (rem > 0) comp(gA0, aA0);
        if (rem > 1) comp(gA1, aA1);
        if (rem > 2) comp(gA2, aA2);
        if (rem > 3) comp(gA3, aA3);
        if (rem > 4) comp(gB0, aB0);
        if (rem > 5) comp(gB1, aB1);
        if (rem > 6) comp(gB2, aB2);
#undef LOAD_BANK

        int* orow = out + (size_t)(b0 + bb) * N;
        if (n0r < N) orow[n0r] = (ACC.x >= 0.0f) ? 1 : 0;
        if (n1r < N) orow[n1r] = (ACC.y >= 0.0f) ? 1 : 0;
    }
}

extern "C" void kernel_launch(void* const* d_in, const int* in_sizes, int n_in,
                              void* d_out, int out_size, void* d_ws, size_t ws_size,
                              hipStream_t stream) {
    const float* anchorss   = (const float*)d_in[0];
    const float* gt_bboxess = (const float*)d_in[1];
    const int*   gt_counts  = (const int*)d_in[2];
    const int*   use_anchor = (const int*)d_in[3];
    int*         out        = (int*)d_out;

    const int B = in_sizes[2];              // gt_counts is (B,1)
    const int A = in_sizes[1] / (4 * B);    // gt_bboxess is (B,A,4)
    const int N = in_sizes[0] / (4 * B);    // anchorss   is (B,N,4)

    dim3 grid((N + BLOCK * IPT - 1) / (BLOCK * IPT), (B + BPB - 1) / BPB);
    size_t smem = (size_t)(BPB * A) * (sizeof(float4) + sizeof(float));
    hipLaunchKernelGGL(assign_cls_label_kernel, grid, dim3(BLOCK), smem, stream,
                       anchorss, gt_bboxess, gt_counts, use_anchor, out, N, A, B);
}

// Round 5
// 95.785 us; speedup vs baseline: 1.1570x; 1.0320x over previous
//
#include <hip/hip_runtime.h>

typedef float f32x2 __attribute__((ext_vector_type(2)));

constexpr int BLOCK = 512;
constexpr int IPT   = 2;   // anchors per thread, packed as one f32x2 lane-pair
constexpr int BPB   = 8;   // ALL batches per block -> 256 identical blocks, 1/CU
constexpr int PAD   = 8;   // staged-gt padding: prefetch never clamps -> imm offsets

__global__ __launch_bounds__(BLOCK, 2) void assign_cls_label_kernel(
    const float* __restrict__ anchorss,   // (B,N,4) y,x,h,w (or y1,x1,y2,x2 if !use_anchor)
    const float* __restrict__ gt_bboxess, // (B,A,4) y1,x1,y2,x2
    const int* __restrict__ gt_counts,    // (B,1)
    const int* __restrict__ use_anchor_p, // scalar
    int* __restrict__ out,                // (B,N)
    int N, int A, int B)
{
#pragma clang fp contract(off)
    extern __shared__ float4 s_box[];     // [BPB][A+PAD]
    __shared__ int s_count[BPB];

    const int AS  = A + PAD;
    const int tid = threadIdx.x;
    const int b0  = blockIdx.y * BPB;
    const int nbA = ((B - b0 < BPB) ? (B - b0) : BPB) * A;

    const int n0r = blockIdx.x * (BLOCK * IPT) + tid;   // lane-contiguous -> coalesced
    const int n1r = n0r + BLOCK;
    const int n0  = (n0r < N) ? n0r : N - 1;            // tail clamp (stores guarded)
    const int n1  = (n1r < N) ? n1r : N - 1;

    // prefetch batch-0 anchors (independent of LDS staging; hides HBM latency)
    float4 an0 = ((const float4*)anchorss)[(size_t)b0 * N + n0];
    float4 an1 = ((const float4*)anchorss)[(size_t)b0 * N + n1];

    // stage gt boxes for all batches; with BLOCK=512 and 8x64 boxes this is 1 iter
    for (int i = tid; i < nbA; i += BLOCK) {
        const int bb = i / A, gi = i - bb * A;
        s_box[bb * AS + gi] = ((const float4*)gt_bboxess)[(size_t)(b0 + bb) * A + gi];
    }
    if (tid < BPB) s_count[tid] = (b0 + tid < B) ? gt_counts[b0 + tid] : 0;

    const int use_anchor = use_anchor_p[0];
    __syncthreads();

    const float c26 = 1.0f / 67108864.0f;  // fl(i/u)>=0.5 <=> i-(0.5-2^-26)u >= 0 (sign-exact)

#pragma clang loop unroll(disable)
    for (int bb = 0; bb < BPB; ++bb) {
        if (b0 + bb >= B) break;                        // uniform
        const float4 ac0 = an0, ac1 = an1;
        if (bb + 1 < BPB && b0 + bb + 1 < B) {          // rolling next-batch prefetch
            const float4* arow = (const float4*)anchorss + (size_t)(b0 + bb + 1) * N;
            an0 = arow[n0];
            an1 = arow[n1];
        }

        f32x2 Y1, X1, Y2, X2, AREA;
        if (use_anchor) {
            const f32x2 H  = {ac0.z, ac1.z};
            const f32x2 W  = {ac0.w, ac1.w};
            const f32x2 Yc = {ac0.x, ac1.x};
            const f32x2 Xc = {ac0.y, ac1.y};
            Y1 = Yc - H * 0.5f;   // h*0.5 exact; one rounded sub == ref's y - h/2
            Y2 = Y1 + H;
            X1 = Xc - W * 0.5f;
            X2 = X1 + W;
            AREA = H * W;
        } else {
            Y1 = f32x2{ac0.x, ac1.x}; X1 = f32x2{ac0.y, ac1.y};
            Y2 = f32x2{ac0.z, ac1.z}; X2 = f32x2{ac0.w, ac1.w};
            AREA = (Y2 - Y1) * (X2 - X1);
        }
        f32x2 ACC = {-1.0f, -1.0f};

        const float4* sb    = s_box + bb * AS;
        const int     count = s_count[bb];

        // one gt vs packed anchor pair: 8 med3 + 3 ga + ~7 packable + 1 max
        auto comp = [&](const float4 g) {
            const float ga = (g.z - g.x) * (g.w - g.y);   // ref op order
            f32x2 yy1, yy2, xx1, xx2;
            yy1.x = __builtin_amdgcn_fmed3f(Y1.x, g.x, g.z);
            yy1.y = __builtin_amdgcn_fmed3f(Y1.y, g.x, g.z);
            yy2.x = __builtin_amdgcn_fmed3f(Y2.x, g.x, g.z);
            yy2.y = __builtin_amdgcn_fmed3f(Y2.y, g.x, g.z);
            xx1.x = __builtin_amdgcn_fmed3f(X1.x, g.y, g.w);
            xx1.y = __builtin_amdgcn_fmed3f(X1.y, g.y, g.w);
            xx2.x = __builtin_amdgcn_fmed3f(X2.x, g.y, g.w);
            xx2.y = __builtin_amdgcn_fmed3f(X2.y, g.y, g.w);
            const f32x2 dy    = yy2 - yy1;
            const f32x2 dx    = xx2 - xx1;
            const f32x2 inter = dy * dx;
            const f32x2 u     = (AREA + ga) - inter;      // ref assoc: (area+ga)-inter
            const f32x2 mh    = {-0.5f, -0.5f};
            const f32x2 cc    = {c26, c26};
            const f32x2 e = __builtin_elementwise_fma(u, mh, inter); // Sterbenz-exact band
            const f32x2 r = __builtin_elementwise_fma(u, cc, e);     // sign-exact decision
            ACC = __builtin_elementwise_max(ACC, r);
        };

        // 4-deep x 2-bank register prefetch; PAD guarantees in-bounds without clamps,
        // so the 4 loads share one address reg + immediate offsets (no per-slot VALU).
        float4 gA0, gA1, gA2, gA3, gB0, gB1, gB2, gB3;
        gA0 = sb[0]; gA1 = sb[1]; gA2 = sb[2]; gA3 = sb[3];
        int gi = 0;
        while (gi + 8 <= count) {
            gB0 = sb[gi + 4]; gB1 = sb[gi + 5]; gB2 = sb[gi + 6]; gB3 = sb[gi + 7];
            comp(gA0); comp(gA1); comp(gA2); comp(gA3);
            gA0 = sb[gi + 8]; gA1 = sb[gi + 9]; gA2 = sb[gi + 10]; gA3 = sb[gi + 11];
            comp(gB0); comp(gB1); comp(gB2); comp(gB3);
            gi += 8;
        }
        const int rem = count - gi;                      // 0..7; bank A holds gi..gi+3
        if (rem > 4) { gB0 = sb[gi + 4]; gB1 = sb[gi + 5]; gB2 = sb[gi + 6]; gB3 = sb[gi + 7]; }
        if (rem > 0) comp(gA0);
        if (rem > 1) comp(gA1);
        if (rem > 2) comp(gA2);
        if (rem > 3) comp(gA3);
        if (rem > 4) comp(gB0);
        if (rem > 5) comp(gB1);
        if (rem > 6) comp(gB2);

        int* orow = out + (size_t)(b0 + bb) * N;
        if (n0r < N) orow[n0r] = (ACC.x >= 0.0f) ? 1 : 0;
        if (n1r < N) orow[n1r] = (ACC.y >= 0.0f) ? 1 : 0;
    }
}

extern "C" void kernel_launch(void* const* d_in, const int* in_sizes, int n_in,
                              void* d_out, int out_size, void* d_ws, size_t ws_size,
                              hipStream_t stream) {
    const float* anchorss   = (const float*)d_in[0];
    const float* gt_bboxess = (const float*)d_in[1];
    const int*   gt_counts  = (const int*)d_in[2];
    const int*   use_anchor = (const int*)d_in[3];
    int*         out        = (int*)d_out;

    const int B = in_sizes[2];              // gt_counts is (B,1)
    const int A = in_sizes[1] / (4 * B);    // gt_bboxess is (B,A,4)
    const int N = in_sizes[0] / (4 * B);    // anchorss   is (B,N,4)

    dim3 grid((N + BLOCK * IPT - 1) / (BLOCK * IPT), (B + BPB - 1) / BPB);
    size_t smem = (size_t)(BPB * (A + PAD)) * sizeof(float4);
    hipLaunchKernelGGL(assign_cls_label_kernel, grid, dim3(BLOCK), smem, stream,
                       anchorss, gt_bboxess, gt_counts, use_anchor, out, N, A, B);
}